// Round 2
// baseline (216.665 us; speedup 1.0000x reference)
//
#include <hip/hip_runtime.h>

#define SM 1028
#define D_ 256
#define S_ 1024
#define B_ 8

// Kernel 1: c[b,d,i] = sum_{w<i} x[b,d,w] * weight[d,i,w]; y = x*(1+relu(c))
// grid: 4096 blocks = 256 d * 16 row-blocks (64 rows), heavy row-blocks first.
// block: 256 threads = 4 waves. Each wave processes 4 row-quads (4 rows each),
// chunking w in 256-wide spans: one global_load_dwordx4 per lane covers a
// contiguous 4 KB span of ONE weight row per instruction (alignment-friendly).
// Final chunk uses per-lane predicated loads so no fetch beyond the causal
// limit (triangle edge slop ~ 1 cache line per row).
__global__ __launch_bounds__(256, 4)
void lie_mix_kernel(const float* __restrict__ x, const float* __restrict__ weight,
                    float* __restrict__ y) {
  int bid = blockIdx.x;
  int d = bid & 255;
  int bi = 15 - (bid >> 8);   // heavy (large i0) blocks get low blockIdx
  int i0 = bi << 6;           // block rows: [i0, i0+64)

  __shared__ float xs[B_][S_];

  int t = threadIdx.x;
  // stage x[b][d][0 .. round256(i0+64)) into LDS (float4, coalesced).
  // Rounded up so masked-chunk LDS reads never hit uninitialized LDS.
  int wlim4 = ((i0 + 64 + 255) & ~255) >> 2;
  for (int bb = 0; bb < B_; ++bb) {
    const float4* src = (const float4*)(x + ((size_t)bb * D_ + d) * S_);
    float4* dst = (float4*)(&xs[bb][0]);
    for (int idx = t; idx < wlim4; idx += 256) dst[idx] = src[idx];
  }
  __syncthreads();

  int lane = t & 63;
  int wid = t >> 6;
  int e0 = lane << 2;               // this lane's element offset within a chunk
  const size_t drow = (size_t)d * SM;

  for (int q = 0; q < 4; ++q) {
    int rq = i0 + ((q << 2) + wid) << 2;  // NOTE: see fix below
    rq = i0 + (((q << 2) + wid) << 2);    // quad base row (4 rows)
    const float* base = weight + (drow + rq) * (size_t)SM;

    float acc[4][8];
#pragma unroll
    for (int k = 0; k < 4; ++k)
#pragma unroll
      for (int b = 0; b < 8; ++b) acc[k][b] = 0.f;

    int cq = rq >> 8;  // number of fully-valid 256-wide chunks

    float4 wc[4];
    if (cq > 0) {
#pragma unroll
      for (int k = 0; k < 4; ++k)
        wc[k] = *(const float4*)(base + (size_t)k * SM + e0);
    }
    for (int c = 0; c < cq; ++c) {
      float4 wn[4];
      if (c + 1 < cq) {
        const float* p = base + ((c + 1) << 8) + e0;
#pragma unroll
        for (int k = 0; k < 4; ++k) wn[k] = *(const float4*)(p + (size_t)k * SM);
      }
      int w0 = c << 8;
#pragma unroll
      for (int b = 0; b < 8; ++b) {
        float4 xb = *(const float4*)&xs[b][w0 + e0];
#pragma unroll
        for (int k = 0; k < 4; ++k) {
          acc[k][b] += xb.x * wc[k].x;
          acc[k][b] += xb.y * wc[k].y;
          acc[k][b] += xb.z * wc[k].z;
          acc[k][b] += xb.w * wc[k].w;
        }
      }
      if (c + 1 < cq) {
#pragma unroll
        for (int k = 0; k < 4; ++k) wc[k] = wn[k];
      }
    }

    // masked chunk c == cq: element w = 256*cq + e valid iff e < limit(row)
    {
      int w0 = cq << 8;
      float4 wm[4];
#pragma unroll
      for (int k = 0; k < 4; ++k) {
        int limit = rq + k - w0;   // elements valid in this chunk for row rq+k
        float4 v = make_float4(0.f, 0.f, 0.f, 0.f);
        if (e0 < limit) v = *(const float4*)(base + (size_t)k * SM + w0 + e0);
        if (e0 + 1 >= limit) v.y = 0.f;
        if (e0 + 2 >= limit) v.z = 0.f;
        if (e0 + 3 >= limit) v.w = 0.f;
        wm[k] = v;
      }
#pragma unroll
      for (int b = 0; b < 8; ++b) {
        float4 xb = *(const float4*)&xs[b][w0 + e0];
#pragma unroll
        for (int k = 0; k < 4; ++k) {
          acc[k][b] += xb.x * wm[k].x;
          acc[k][b] += xb.y * wm[k].y;
          acc[k][b] += xb.z * wm[k].z;
          acc[k][b] += xb.w * wm[k].w;
        }
      }
    }

    // full 64-lane butterfly reduce; every lane ends with all 32 sums
#pragma unroll
    for (int s = 1; s < 64; s <<= 1) {
#pragma unroll
      for (int k = 0; k < 4; ++k)
#pragma unroll
        for (int b = 0; b < 8; ++b)
          acc[k][b] += __shfl_xor(acc[k][b], s, 64);
    }

    // lane (k*8+b) stores row rq+k, batch b
    float v = 0.f;
#pragma unroll
    for (int k = 0; k < 4; ++k)
#pragma unroll
      for (int b = 0; b < 8; ++b)
        v = (lane == (k << 3) + b) ? acc[k][b] : v;
    if (lane < 32) {
      int k = lane >> 3, b = lane & 7;
      float xv = xs[b][rq + k];
      y[((size_t)b * D_ + d) * S_ + rq + k] = xv * (1.f + fmaxf(v, 0.f));
    }
  }
}

// Kernel 2: LayerNorm over channel axis d (size 256) per (b, s).
__global__ __launch_bounds__(256)
void ln_kernel(const float* __restrict__ y, const float* __restrict__ gamma,
               const float* __restrict__ beta, float* __restrict__ out) {
  __shared__ float tile[D_][33];
  __shared__ float ps[8][32];
  __shared__ float pq[8][32];
  __shared__ float mu[32];
  __shared__ float rs[32];
  int b = blockIdx.x >> 5;
  int s0 = (blockIdx.x & 31) << 5;
  int t = threadIdx.x;
  int sj = t & 31, dq = t >> 5;
  for (int dd = dq; dd < D_; dd += 8)
    tile[dd][sj] = y[((size_t)b * D_ + dd) * S_ + s0 + sj];
  __syncthreads();
  float sm = 0.f, sq = 0.f;
#pragma unroll 8
  for (int r = 0; r < 32; ++r) {
    float v = tile[dq * 32 + r][sj];
    sm += v;
    sq += v * v;
  }
  ps[dq][sj] = sm;
  pq[dq][sj] = sq;
  __syncthreads();
  if (t < 32) {
    float S = 0.f, Q = 0.f;
#pragma unroll
    for (int q = 0; q < 8; ++q) { S += ps[q][t]; Q += pq[q][t]; }
    float m = S * (1.f / 256.f);
    float var = Q * (1.f / 256.f) - m * m;
    mu[t] = m;
    rs[t] = rsqrtf(var + 1e-5f);
  }
  __syncthreads();
  for (int dd = dq; dd < D_; dd += 8) {
    float v = tile[dd][sj];
    out[((size_t)b * D_ + dd) * S_ + s0 + sj] =
        (v - mu[sj]) * rs[sj] * gamma[dd] + beta[dd];
  }
}

extern "C" void kernel_launch(void* const* d_in, const int* in_sizes, int n_in,
                              void* d_out, int out_size, void* d_ws, size_t ws_size,
                              hipStream_t stream) {
  const float* x = (const float*)d_in[0];
  const float* weight = (const float*)d_in[1];
  const float* gamma = (const float*)d_in[2];
  const float* beta = (const float*)d_in[3];
  float* out = (float*)d_out;
  float* y = (float*)d_ws;  // 8*256*1024 f32 = 8 MB scratch

  lie_mix_kernel<<<4096, 256, 0, stream>>>(x, weight, y);
  ln_kernel<<<256, 256, 0, stream>>>(y, gamma, beta, out);
}

// Round 3
// 204.627 us; speedup vs baseline: 1.0588x; 1.0588x over previous
//
#include <hip/hip_runtime.h>

#define SM 1028
#define D_ 256
#define S_ 1024
#define B_ 8

// Kernel 1: c[b,d,i] = sum_{w<i} x[b,d,w] * weight[d,i,w]; y = x*(1+relu(c))
// grid: 1024 blocks = 256 d * 4 row-blocks (256 rows each) -> exactly 4/CU.
// block: 256 threads = 4 waves; each wave owns 64 rows as 16 groups of 4
// lanes x 4 rows. Chunk = 16 floats (4 lanes x float4): per k-instruction the
// wave loads 16 x 64 B row-segments (line-sized, streamed sequentially so the
// 16 B phase-straddle is amortized in L2). Reduction radix 4 -> only 2
// shfl_xor steps per accumulator (1 DS op per output row vs 8 in round 1).
__global__ __launch_bounds__(256, 4)
void lie_mix_kernel(const float* __restrict__ x, const float* __restrict__ weight,
                    float* __restrict__ y) {
  int bid = blockIdx.x;
  int d = bid & 255;
  int bi = 3 - (bid >> 8);    // heavy row-blocks get low blockIdx
  int i0 = bi << 8;           // block rows: [i0, i0+256)

  __shared__ float xs[B_][S_];

  int t = threadIdx.x;
  // stage x[b][d][0..1024) into LDS: 256 threads x 1 float4 per batch
#pragma unroll
  for (int bb = 0; bb < B_; ++bb) {
    const float4* src = (const float4*)(x + ((size_t)bb * D_ + d) * S_);
    ((float4*)&xs[bb][0])[t] = src[t];
  }
  __syncthreads();

  int lane = t & 63;
  int wid = t >> 6;
  int g = lane >> 2;                // 16 groups of 4 lanes per wave
  int j = lane & 3;                 // lane within group
  int e0 = j << 2;                  // element offset within a 16-wide chunk
  int wb = i0 + (wid << 6);         // wave rows: [wb, wb+64)
  int rq = wb + (g << 2);           // group rows: [rq, rq+4)

  const float* base = weight + ((size_t)d * SM + rq) * SM + e0;

  float acc[4][8];
#pragma unroll
  for (int k = 0; k < 4; ++k)
#pragma unroll
    for (int b = 0; b < 8; ++b) acc[k][b] = 0.f;

  int F = wb >> 4;  // full 16-wide chunks (uniform per wave)

  for (int c = 0; c < F; ++c) {
    int w0 = c << 4;
    float4 wc[4];
#pragma unroll
    for (int k = 0; k < 4; ++k)
      wc[k] = *(const float4*)(base + (size_t)k * SM + w0);
#pragma unroll
    for (int b = 0; b < 8; ++b) {
      float4 xb = *(const float4*)&xs[b][w0 + e0];
#pragma unroll
      for (int k = 0; k < 4; ++k) {
        acc[k][b] += xb.x * wc[k].x;
        acc[k][b] += xb.y * wc[k].y;
        acc[k][b] += xb.z * wc[k].z;
        acc[k][b] += xb.w * wc[k].w;
      }
    }
  }

  // epilogue: 4 chunks [16F, 16F+64) cover every group's remaining range.
  // Per-lane predicated loads: nothing is fetched past the causal limit.
#pragma unroll
  for (int ec = 0; ec < 4; ++ec) {
    int w0 = (F + ec) << 4;
    float4 wm[4];
#pragma unroll
    for (int k = 0; k < 4; ++k) {
      int limit = rq + k - w0;  // valid elements in this chunk for row rq+k
      float4 v = make_float4(0.f, 0.f, 0.f, 0.f);
      if (e0 < limit) v = *(const float4*)(base + (size_t)k * SM + w0);
      if (e0 + 1 >= limit) v.y = 0.f;
      if (e0 + 2 >= limit) v.z = 0.f;
      if (e0 + 3 >= limit) v.w = 0.f;
      wm[k] = v;
    }
#pragma unroll
    for (int b = 0; b < 8; ++b) {
      float4 xb = *(const float4*)&xs[b][w0 + e0];
#pragma unroll
      for (int k = 0; k < 4; ++k) {
        acc[k][b] += xb.x * wm[k].x;
        acc[k][b] += xb.y * wm[k].y;
        acc[k][b] += xb.z * wm[k].z;
        acc[k][b] += xb.w * wm[k].w;
      }
    }
  }
  // NOTE: base advances by w0 via immediate-free adds; epilogue loads use
  // base + k*SM + w0 directly (w0 = F*16+.. still in-register arithmetic).

  // reduce across the 4 lanes of each group (xor 1, 2 stay in-group)
#pragma unroll
  for (int s = 1; s < 4; s <<= 1) {
#pragma unroll
    for (int k = 0; k < 4; ++k)
#pragma unroll
      for (int b = 0; b < 8; ++b)
        acc[k][b] += __shfl_xor(acc[k][b], s, 64);
  }

  // lane j writes batches j and j+4 for the group's 4 rows as float4
  {
    int b0 = j, b1 = j + 4;
    float4 o0, o1;
    float4 x0 = *(const float4*)&xs[b0][rq];
    float4 x1 = *(const float4*)&xs[b1][rq];
    o0.x = x0.x * (1.f + fmaxf(acc[0][b0], 0.f));
    o0.y = x0.y * (1.f + fmaxf(acc[1][b0], 0.f));
    o0.z = x0.z * (1.f + fmaxf(acc[2][b0], 0.f));
    o0.w = x0.w * (1.f + fmaxf(acc[3][b0], 0.f));
    o1.x = x1.x * (1.f + fmaxf(acc[0][b1], 0.f));
    o1.y = x1.y * (1.f + fmaxf(acc[1][b1], 0.f));
    o1.z = x1.z * (1.f + fmaxf(acc[2][b1], 0.f));
    o1.w = x1.w * (1.f + fmaxf(acc[3][b1], 0.f));
    *(float4*)(y + ((size_t)b0 * D_ + d) * S_ + rq) = o0;
    *(float4*)(y + ((size_t)b1 * D_ + d) * S_ + rq) = o1;
  }
}

// Kernel 2: LayerNorm over channel axis d (size 256) per (b, s).
__global__ __launch_bounds__(256)
void ln_kernel(const float* __restrict__ y, const float* __restrict__ gamma,
               const float* __restrict__ beta, float* __restrict__ out) {
  __shared__ float tile[D_][33];
  __shared__ float ps[8][32];
  __shared__ float pq[8][32];
  __shared__ float mu[32];
  __shared__ float rs[32];
  int b = blockIdx.x >> 5;
  int s0 = (blockIdx.x & 31) << 5;
  int t = threadIdx.x;
  int sj = t & 31, dq = t >> 5;
  for (int dd = dq; dd < D_; dd += 8)
    tile[dd][sj] = y[((size_t)b * D_ + dd) * S_ + s0 + sj];
  __syncthreads();
  float sm = 0.f, sq = 0.f;
#pragma unroll 8
  for (int r = 0; r < 32; ++r) {
    float v = tile[dq * 32 + r][sj];
    sm += v;
    sq += v * v;
  }
  ps[dq][sj] = sm;
  pq[dq][sj] = sq;
  __syncthreads();
  if (t < 32) {
    float S = 0.f, Q = 0.f;
#pragma unroll
    for (int q = 0; q < 8; ++q) { S += ps[q][t]; Q += pq[q][t]; }
    float m = S * (1.f / 256.f);
    float var = Q * (1.f / 256.f) - m * m;
    mu[t] = m;
    rs[t] = rsqrtf(var + 1e-5f);
  }
  __syncthreads();
  for (int dd = dq; dd < D_; dd += 8) {
    float v = tile[dd][sj];
    out[((size_t)b * D_ + dd) * S_ + s0 + sj] =
        (v - mu[sj]) * rs[sj] * gamma[dd] + beta[dd];
  }
}

extern "C" void kernel_launch(void* const* d_in, const int* in_sizes, int n_in,
                              void* d_out, int out_size, void* d_ws, size_t ws_size,
                              hipStream_t stream) {
  const float* x = (const float*)d_in[0];
  const float* weight = (const float*)d_in[1];
  const float* gamma = (const float*)d_in[2];
  const float* beta = (const float*)d_in[3];
  float* out = (float*)d_out;
  float* y = (float*)d_ws;  // 8*256*1024 f32 = 8 MB scratch

  lie_mix_kernel<<<1024, 256, 0, stream>>>(x, weight, y);
  ln_kernel<<<256, 256, 0, stream>>>(y, gamma, beta, out);
}

// Round 4
// 151.314 us; speedup vs baseline: 1.4319x; 1.3523x over previous
//
#include <hip/hip_runtime.h>

#define SM 1028
#define D_ 256
#define S_ 1024
#define B_ 8

// Kernel 1: c[b,d,i] = sum_{w<i} x[b,d,w] * weight[d,i,w]; y = x*(1+relu(c))
// grid: 1024 blocks = 256 d * 4 row-blocks (256 rows). block: 256 thr = 4 waves.
// Wave owns 64 rows as 16 groups x 4 lanes. Group (q,m) owns rows
// r0=wb+m+16q + {0,4,8,12} -- all with byte phase 16*m (row stride 4112 B =
// 16 mod 64, phase depends only on i mod 4). The group's 16-elem chunk grid is
// shifted by a_m=(16-4m)&15 elements so EVERY 64 B group-span is line-aligned:
// zero straddle, every fetched line fully consumed. x-window per lane is
// uniform across its 4 rows -> 8 xb LDS reads shared (no LDS amplification).
// Ragged causal edges: 1 predicated prologue chunk + 2 predicated epilogue
// chunks (no fetch beyond the triangle). Reduction: radix-4 shfl_xor.
__global__ __launch_bounds__(256, 4)
void lie_mix_kernel(const float* __restrict__ x, const float* __restrict__ weight,
                    float* __restrict__ y) {
  int bid = blockIdx.x;
  int d = bid & 255;
  int bi = 3 - (bid >> 8);    // heavy row-blocks get low blockIdx
  int i0 = bi << 8;           // block rows: [i0, i0+256)

  __shared__ __align__(16) float xs[B_][1040];  // 16-elem zero pad per row

  int t = threadIdx.x;
#pragma unroll
  for (int bb = 0; bb < B_; ++bb) {
    const float4* src = (const float4*)(x + ((size_t)bb * D_ + d) * S_);
    *(float4*)&xs[bb][t << 2] = src[t];
  }
  if (t < 32)
    *(float4*)&xs[t >> 2][1024 + ((t & 3) << 2)] = make_float4(0.f, 0.f, 0.f, 0.f);
  __syncthreads();

  int lane = t & 63;
  int wid = t >> 6;
  int wb = i0 + (wid << 6);          // wave rows: [wb, wb+64)
  int g = lane >> 2;                 // 16 groups of 4 lanes
  int j = lane & 3;                  // lane within group
  int m = g & 3;                     // phase class (rows == m mod 4)
  int q = g >> 2;
  int r0 = wb + m + (q << 4);        // lane's rows: r0 + 4k, k=0..3
  int a = (16 - (m << 2)) & 15;      // aligned chunk-grid shift (elements)

  const float* wptr = weight + ((size_t)d * SM + r0) * SM + a + (j << 2);

  float acc[4][8];
#pragma unroll
  for (int k = 0; k < 4; ++k)
#pragma unroll
    for (int b = 0; b < 8; ++b) acc[k][b] = 0.f;

  // ---- prologue: elements [0, a) (line-aligned window [a-16, a)) ----
  if (a > 0) {
    int e_s = a - 16 + (j << 2);
    if (e_s >= 0) {                  // float4 fully within [0, a)
      float4 xb[8];
#pragma unroll
      for (int b = 0; b < 8; ++b) xb[b] = *(const float4*)&xs[b][e_s];
#pragma unroll
      for (int k = 0; k < 4; ++k) {
        int rk = r0 + (k << 2);
        float4 v = make_float4(0.f, 0.f, 0.f, 0.f);
        if (e_s < rk) v = *(const float4*)(wptr - 16 + (size_t)(k * 4) * SM);
        if (e_s + 1 >= rk) v.y = 0.f;
        if (e_s + 2 >= rk) v.z = 0.f;
        if (e_s + 3 >= rk) v.w = 0.f;
#pragma unroll
        for (int b = 0; b < 8; ++b)
          acc[k][b] += xb[b].x * v.x + xb[b].y * v.y + xb[b].z * v.z + xb[b].w * v.w;
      }
    }
  }

  // ---- main loop: full 16-elem chunks, all loads 64 B line-aligned ----
  int F = (r0 - a) >> 4;
  if (F < 0) F = 0;
  for (int c = 0; c < F; ++c) {
    int e = a + (c << 4) + (j << 2);
    float4 wc[4];
#pragma unroll
    for (int k = 0; k < 4; ++k)
      wc[k] = *(const float4*)(wptr + (size_t)(k * 4) * SM + (c << 4));
#pragma unroll
    for (int b = 0; b < 8; ++b) {
      float4 xb = *(const float4*)&xs[b][e];
#pragma unroll
      for (int k = 0; k < 4; ++k) {
        acc[k][b] += xb.x * wc[k].x + xb.y * wc[k].y + xb.z * wc[k].z + xb.w * wc[k].w;
      }
    }
  }

  // ---- epilogue: 2 predicated chunks cover [a+16F, rk) for all 4 rows ----
#pragma unroll
  for (int ec = 0; ec < 2; ++ec) {
    int c = F + ec;
    int e_s = a + (c << 4) + (j << 2);
    float4 wm[4];
#pragma unroll
    for (int k = 0; k < 4; ++k) {
      int rk = r0 + (k << 2);
      float4 v = make_float4(0.f, 0.f, 0.f, 0.f);
      if (e_s < rk) v = *(const float4*)(wptr + (size_t)(k * 4) * SM + (c << 4));
      if (e_s + 1 >= rk) v.y = 0.f;
      if (e_s + 2 >= rk) v.z = 0.f;
      if (e_s + 3 >= rk) v.w = 0.f;
      wm[k] = v;
    }
#pragma unroll
    for (int b = 0; b < 8; ++b) {
      float4 xb = *(const float4*)&xs[b][e_s];  // <=1027, inside zeroed pad
#pragma unroll
      for (int k = 0; k < 4; ++k) {
        acc[k][b] += xb.x * wm[k].x + xb.y * wm[k].y + xb.z * wm[k].z + xb.w * wm[k].w;
      }
    }
  }

  // ---- reduce across the 4 lanes of each group (xor 1,2 stay in-group) ----
#pragma unroll
  for (int s = 1; s < 4; s <<= 1)
#pragma unroll
    for (int k = 0; k < 4; ++k)
#pragma unroll
      for (int b = 0; b < 8; ++b)
        acc[k][b] += __shfl_xor(acc[k][b], s, 64);

  // lane j writes batches j and j+4 for its 4 (strided) rows
  {
    int b0 = j, b1 = j + 4;
#pragma unroll
    for (int k = 0; k < 4; ++k) {
      int r = r0 + (k << 2);
      float x0 = xs[b0][r], x1 = xs[b1][r];
      y[((size_t)b0 * D_ + d) * S_ + r] = x0 * (1.f + fmaxf(acc[k][b0], 0.f));
      y[((size_t)b1 * D_ + d) * S_ + r] = x1 * (1.f + fmaxf(acc[k][b1], 0.f));
    }
  }
}

// Kernel 2: LayerNorm over channel axis d (size 256) per (b, s).
__global__ __launch_bounds__(256)
void ln_kernel(const float* __restrict__ y, const float* __restrict__ gamma,
               const float* __restrict__ beta, float* __restrict__ out) {
  __shared__ float tile[D_][33];
  __shared__ float ps[8][32];
  __shared__ float pq[8][32];
  __shared__ float mu[32];
  __shared__ float rs[32];
  int b = blockIdx.x >> 5;
  int s0 = (blockIdx.x & 31) << 5;
  int t = threadIdx.x;
  int sj = t & 31, dq = t >> 5;
  for (int dd = dq; dd < D_; dd += 8)
    tile[dd][sj] = y[((size_t)b * D_ + dd) * S_ + s0 + sj];
  __syncthreads();
  float sm = 0.f, sq = 0.f;
#pragma unroll 8
  for (int r = 0; r < 32; ++r) {
    float v = tile[dq * 32 + r][sj];
    sm += v;
    sq += v * v;
  }
  ps[dq][sj] = sm;
  pq[dq][sj] = sq;
  __syncthreads();
  if (t < 32) {
    float S = 0.f, Q = 0.f;
#pragma unroll
    for (int qq = 0; qq < 8; ++qq) { S += ps[qq][t]; Q += pq[qq][t]; }
    float mm = S * (1.f / 256.f);
    float var = Q * (1.f / 256.f) - mm * mm;
    mu[t] = mm;
    rs[t] = rsqrtf(var + 1e-5f);
  }
  __syncthreads();
  for (int dd = dq; dd < D_; dd += 8) {
    float v = tile[dd][sj];
    out[((size_t)b * D_ + dd) * S_ + s0 + sj] =
        (v - mu[sj]) * rs[sj] * gamma[dd] + beta[dd];
  }
}

extern "C" void kernel_launch(void* const* d_in, const int* in_sizes, int n_in,
                              void* d_out, int out_size, void* d_ws, size_t ws_size,
                              hipStream_t stream) {
  const float* x = (const float*)d_in[0];
  const float* weight = (const float*)d_in[1];
  const float* gamma = (const float*)d_in[2];
  const float* beta = (const float*)d_in[3];
  float* out = (float*)d_out;
  float* y = (float*)d_ws;  // 8*256*1024 f32 = 8 MB scratch

  lie_mix_kernel<<<1024, 256, 0, stream>>>(x, weight, y);
  ln_kernel<<<256, 256, 0, stream>>>(y, gamma, beta, out);
}